// Round 1
// baseline (598.121 us; speedup 1.0000x reference)
//
#include <hip/hip_runtime.h>

using u16 = unsigned short;
typedef __attribute__((ext_vector_type(8))) short bf16x8;
typedef __attribute__((ext_vector_type(4))) float f32x4;
typedef __attribute__((ext_vector_type(4))) float float4v;
typedef __attribute__((ext_vector_type(4))) unsigned short us4;

__device__ __forceinline__ u16 f2bf(float f) {
  union { float f; unsigned u; } v; v.f = f;
  unsigned r = v.u + 0x7fffu + ((v.u >> 16) & 1u);
  return (u16)(r >> 16);
}

__device__ __forceinline__ void glds16(const void* g, void* l) {
  __builtin_amdgcn_global_load_lds(
      (const __attribute__((address_space(1))) void*)g,
      (__attribute__((address_space(3))) void*)l, 16, 0, 0);
}

#define MFMA(a, b, c) __builtin_amdgcn_mfma_f32_16x16x32_bf16((a), (b), (c), 0, 0, 0)

// ---------------- fp32 -> bf16 cast (vector x4) ----------------
__global__ __launch_bounds__(256) void cvt_bf16(const float* __restrict__ src,
                                                u16* __restrict__ dst, int n4) {
  int i = blockIdx.x * 256 + threadIdx.x;
  if (i >= n4) return;
  float4v v = ((const float4v*)src)[i];
  us4 o;
  o[0] = f2bf(v[0]); o[1] = f2bf(v[1]); o[2] = f2bf(v[2]); o[3] = f2bf(v[3]);
  ((us4*)dst)[i] = o;
}

// ---------------- RoPE tables: (L=2048, 32) ----------------
__global__ __launch_bounds__(256) void rope_tables(float* __restrict__ cos_t,
                                                   float* __restrict__ sin_t) {
  int i = blockIdx.x * 256 + threadIdx.x;
  if (i >= 2048 * 32) return;
  int t = i >> 5, fi = i & 31;
  float inv = powf(10000.f, -(float)fi / 32.f);
  float ang = (float)t * inv;
  cos_t[i] = cosf(ang);
  sin_t[i] = sinf(ang);
}

// ---------------- bf16 GEMM, C = A(MxK) * B(NxK)^T, fp32 out ----------------
// 128x128 tile, 4 waves (2x2), BK=32, global_load_lds staging (m97 structure)
__global__ __launch_bounds__(256) void gemm_bt(const u16* __restrict__ A,
                                               const u16* __restrict__ B,
                                               float* __restrict__ C,
                                               int M, int N, int K) {
  __shared__ u16 As[128 * 32];
  __shared__ u16 Bs[128 * 32];
  const int tid = threadIdx.x;
  const int w = tid >> 6, l = tid & 63;
  const int wr = w >> 1, wc = w & 1;
  const int lrow = l & 15, lk = (l >> 4) * 8, jr = (l >> 4) * 4;

  f32x4 acc[4][4];
#pragma unroll
  for (int m = 0; m < 4; ++m)
#pragma unroll
    for (int n = 0; n < 4; ++n) acc[m][n] = f32x4{0.f, 0.f, 0.f, 0.f};

  const int st_row = tid >> 2;        // 0..63 (each row of tile = 64B = 4 lanes)
  const int st_k = (tid & 3) * 8;     // bf16 element offset within k-slab
  const u16* a0 = A + (size_t)(blockIdx.x * 128 + st_row) * K + st_k;
  const u16* a1 = a0 + (size_t)64 * K;
  const u16* b0 = B + (size_t)(blockIdx.y * 128 + st_row) * K + st_k;
  const u16* b1 = b0 + (size_t)64 * K;

  u16* Ad0 = &As[w * 512];
  u16* Ad1 = &As[2048 + w * 512];
  u16* Bd0 = &Bs[w * 512];
  u16* Bd1 = &Bs[2048 + w * 512];

  for (int k0 = 0; k0 < K; k0 += 32) {
    glds16(a0, Ad0);
    glds16(a1, Ad1);
    glds16(b0, Bd0);
    glds16(b1, Bd1);
    a0 += 32; a1 += 32; b0 += 32; b1 += 32;
    __syncthreads();
    bf16x8 af[4], bfr[4];
#pragma unroll
    for (int m = 0; m < 4; ++m)
      af[m] = *(const bf16x8*)&As[(wr * 64 + m * 16 + lrow) * 32 + lk];
#pragma unroll
    for (int n = 0; n < 4; ++n)
      bfr[n] = *(const bf16x8*)&Bs[(wc * 64 + n * 16 + lrow) * 32 + lk];
#pragma unroll
    for (int m = 0; m < 4; ++m)
#pragma unroll
      for (int n = 0; n < 4; ++n)
        acc[m][n] = MFMA(af[m], bfr[n], acc[m][n]);
    __syncthreads();
  }

  float* Cp = C + (size_t)(blockIdx.x * 128 + wr * 64) * N + blockIdx.y * 128 + wc * 64;
#pragma unroll
  for (int m = 0; m < 4; ++m)
#pragma unroll
    for (int n = 0; n < 4; ++n)
#pragma unroll
      for (int j = 0; j < 4; ++j)
        Cp[(size_t)(m * 16 + jr + j) * N + n * 16 + lrow] = acc[m][n][j];
}

// ---------------- RoPE apply + layout: qkv(B*L,3072) f32 -> bf16 tensors ----
// q_r: (B,32,L,64), k_r: (B,8,L,64), v_t: (B,8,64,L)  (V transposed!)
__global__ __launch_bounds__(256) void rope_apply(
    const float* __restrict__ qkv, const float* __restrict__ cos_t,
    const float* __restrict__ sin_t, u16* __restrict__ q_r,
    u16* __restrict__ k_r, u16* __restrict__ v_t) {
  int idx = blockIdx.x * 256 + threadIdx.x;
  if (idx >= 2 * 2048 * 3072) return;
  int c = idx % 3072;
  int bl = idx / 3072;         // b*2048 + l
  int l = bl & 2047, b = bl >> 11;
  float val = qkv[idx];
  if (c < 2048) {              // Q
    int h = c >> 6, d = c & 63;
    float cs = cos_t[l * 32 + (d & 31)];
    float sn = sin_t[l * 32 + (d & 31)];
    float other = qkv[(size_t)bl * 3072 + h * 64 + ((d < 32) ? d + 32 : d - 32)];
    float r = (d < 32) ? (val * cs - other * sn) : (val * cs + other * sn);
    q_r[(((size_t)b * 32 + h) * 2048 + l) * 64 + d] = f2bf(r);
  } else if (c < 2560) {       // K
    int cc = c - 2048, h = cc >> 6, d = cc & 63;
    float cs = cos_t[l * 32 + (d & 31)];
    float sn = sin_t[l * 32 + (d & 31)];
    float other = qkv[(size_t)bl * 3072 + 2048 + h * 64 + ((d < 32) ? d + 32 : d - 32)];
    float r = (d < 32) ? (val * cs - other * sn) : (val * cs + other * sn);
    k_r[(((size_t)b * 8 + h) * 2048 + l) * 64 + d] = f2bf(r);
  } else {                     // V (transposed store)
    int cc = c - 2560, h = cc >> 6, d = cc & 63;
    v_t[(((size_t)b * 8 + h) * 64 + d) * 2048 + l] = f2bf(val);
  }
}

// ---------------- causal GQA flash attention ----------------
// 1 wave/block, 16 q-rows per block, kv tiles of 32, online softmax.
// out: attn_o (B, L, 32*64) bf16
__global__ __launch_bounds__(64) void attn(const u16* __restrict__ q_r,
                                           const u16* __restrict__ k_r,
                                           const u16* __restrict__ v_t,
                                           u16* __restrict__ attn_o) {
  __shared__ u16 Pl[16 * 32];
  const int blk = blockIdx.x;       // ((b*32 + h)*128 + qt)
  const int qt = blk & 127;
  const int bh = blk >> 7;
  const int h = bh & 31, b = bh >> 5;
  const int q0 = qt * 16;
  const int l = threadIdx.x;
  const int lrow = l & 15, lk = (l >> 4) * 8, jr = (l >> 4) * 4;
  const int kh = h >> 2;            // GQA: 4 q-heads per kv-head

  const u16* Qp = q_r + (((size_t)(b * 32 + h)) * 2048 + q0) * 64;
  const u16* Kp = k_r + ((size_t)(b * 8 + kh)) * 2048 * 64;
  const u16* Vp = v_t + ((size_t)(b * 8 + kh)) * 64 * 2048;

  // Q fragments held in registers for the whole kernel (2 k-steps of 32)
  bf16x8 aq0 = *(const bf16x8*)&Qp[lrow * 64 + lk];
  bf16x8 aq1 = *(const bf16x8*)&Qp[lrow * 64 + 32 + lk];

  f32x4 o[4];
#pragma unroll
  for (int n = 0; n < 4; ++n) o[n] = f32x4{0.f, 0.f, 0.f, 0.f};
  float mrow[4] = {-1e30f, -1e30f, -1e30f, -1e30f};
  float lsum[4] = {0.f, 0.f, 0.f, 0.f};

  const int ntile = (q0 + 47) >> 5;   // causal: cover kv rows 0 .. q0+15
  for (int t = 0; t < ntile; ++t) {
    const int kv0 = t * 32;
    f32x4 s0 = f32x4{0.f, 0.f, 0.f, 0.f};
    f32x4 s1 = f32x4{0.f, 0.f, 0.f, 0.f};
    {
      const u16* kp0 = Kp + (size_t)(kv0 + lrow) * 64 + lk;
      const u16* kp1 = Kp + (size_t)(kv0 + 16 + lrow) * 64 + lk;
      bf16x8 k00 = *(const bf16x8*)kp0;
      bf16x8 k01 = *(const bf16x8*)(kp0 + 32);
      bf16x8 k10 = *(const bf16x8*)kp1;
      bf16x8 k11 = *(const bf16x8*)(kp1 + 32);
      s0 = MFMA(aq0, k00, s0);
      s0 = MFMA(aq1, k01, s0);
      s1 = MFMA(aq0, k10, s1);
      s1 = MFMA(aq1, k11, s1);
    }
    float alpha[4];
#pragma unroll
    for (int j = 0; j < 4; ++j) {
      const int row = q0 + jr + j;
      float v0 = (kv0 + lrow > row) ? -1e30f : s0[j] * 0.125f;
      float v1 = (kv0 + 16 + lrow > row) ? -1e30f : s1[j] * 0.125f;
      float pm = fmaxf(v0, v1);
      pm = fmaxf(pm, __shfl_xor(pm, 1));
      pm = fmaxf(pm, __shfl_xor(pm, 2));
      pm = fmaxf(pm, __shfl_xor(pm, 4));
      pm = fmaxf(pm, __shfl_xor(pm, 8));
      const float mnew = fmaxf(mrow[j], pm);
      alpha[j] = __expf(mrow[j] - mnew);
      mrow[j] = mnew;
      const float p0 = __expf(v0 - mnew);
      const float p1 = __expf(v1 - mnew);
      float rs = p0 + p1;
      rs += __shfl_xor(rs, 1);
      rs += __shfl_xor(rs, 2);
      rs += __shfl_xor(rs, 4);
      rs += __shfl_xor(rs, 8);
      lsum[j] = lsum[j] * alpha[j] + rs;
      // write P (fp32->bf16) transposed into A-fragment layout via LDS
      Pl[(jr + j) * 32 + lrow] = f2bf(p0);
      Pl[(jr + j) * 32 + 16 + lrow] = f2bf(p1);
    }
    __syncthreads();
    bf16x8 pa = *(const bf16x8*)&Pl[lrow * 32 + lk];
    __syncthreads();
#pragma unroll
    for (int n = 0; n < 4; ++n) {
#pragma unroll
      for (int j = 0; j < 4; ++j) o[n][j] *= alpha[j];
      // V^T rows are output dims: contiguous 16B B-fragment load
      bf16x8 bv = *(const bf16x8*)&Vp[(size_t)(n * 16 + lrow) * 2048 + kv0 + lk];
      o[n] = MFMA(pa, bv, o[n]);
    }
  }
  u16* Op = attn_o + ((size_t)b * 2048 + q0) * 2048 + h * 64;
#pragma unroll
  for (int n = 0; n < 4; ++n)
#pragma unroll
    for (int j = 0; j < 4; ++j)
      Op[(size_t)(jr + j) * 2048 + n * 16 + lrow] = f2bf(o[n][j] / lsum[j]);
}

// ---------------- launch ----------------
extern "C" void kernel_launch(void* const* d_in, const int* in_sizes, int n_in,
                              void* d_out, int out_size, void* d_ws, size_t ws_size,
                              hipStream_t stream) {
  const float* x = (const float*)d_in[0];
  const float* wq = (const float*)d_in[1];
  const float* wk = (const float*)d_in[2];
  const float* wv = (const float*)d_in[3];
  const float* wo = (const float*)d_in[4];
  float* out = (float*)d_out;

  char* p = (char*)d_ws;
  auto alloc = [&](size_t bytes) {
    char* r = p;
    p += (bytes + 255) & ~(size_t)255;
    return r;
  };
  u16* x_bf   = (u16*)alloc((size_t)8388608 * 2);        // x bf16 (4096x2048)
  u16* wqkv   = (u16*)alloc((size_t)3072 * 2048 * 2);    // wq|wk|wv bf16
  u16* wo_bf  = (u16*)alloc((size_t)2048 * 2048 * 2);    // wo bf16
  float* qkv  = (float*)alloc((size_t)4096 * 3072 * 4);  // projections fp32
  u16* q_r    = (u16*)alloc((size_t)8388608 * 2);        // (B,32,L,64)
  u16* k_r    = (u16*)alloc((size_t)2097152 * 2);        // (B,8,L,64)
  u16* v_t    = (u16*)alloc((size_t)2097152 * 2);        // (B,8,64,L)
  u16* attn_o = (u16*)alloc((size_t)8388608 * 2);        // (B,L,2048)
  float* cos_t = (float*)alloc((size_t)65536 * 4);       // (L,32)
  float* sin_t = (float*)alloc((size_t)65536 * 4);

  cvt_bf16<<<8192, 256, 0, stream>>>(x, x_bf, 2097152);
  cvt_bf16<<<4096, 256, 0, stream>>>(wq, wqkv, 1048576);
  cvt_bf16<<<1024, 256, 0, stream>>>(wk, wqkv + (size_t)2048 * 2048, 262144);
  cvt_bf16<<<1024, 256, 0, stream>>>(wv, wqkv + (size_t)2560 * 2048, 262144);
  cvt_bf16<<<4096, 256, 0, stream>>>(wo, wo_bf, 1048576);
  rope_tables<<<256, 256, 0, stream>>>(cos_t, sin_t);

  // QKV projection: (4096x2048) x (3072x2048)^T -> (4096x3072)
  gemm_bt<<<dim3(32, 24), 256, 0, stream>>>(x_bf, wqkv, qkv, 4096, 3072, 2048);

  rope_apply<<<49152, 256, 0, stream>>>(qkv, cos_t, sin_t, q_r, k_r, v_t);

  attn<<<8192, 64, 0, stream>>>(q_r, k_r, v_t, attn_o);

  // output projection: (4096x2048) x (2048x2048)^T -> (4096x2048)
  gemm_bt<<<dim3(32, 16), 256, 0, stream>>>(attn_o, wo_bf, out, 4096, 2048, 2048);
}

// Round 2
// 372.743 us; speedup vs baseline: 1.6046x; 1.6046x over previous
//
#include <hip/hip_runtime.h>

using u16 = unsigned short;
typedef __attribute__((ext_vector_type(8))) short bf16x8;
typedef __attribute__((ext_vector_type(4))) float f32x4;
typedef __attribute__((ext_vector_type(4))) float float4v;
typedef __attribute__((ext_vector_type(4))) unsigned short us4;

__device__ __forceinline__ u16 f2bf(float f) {
  union { float f; unsigned u; } v; v.f = f;
  unsigned r = v.u + 0x7fffu + ((v.u >> 16) & 1u);
  return (u16)(r >> 16);
}

__device__ __forceinline__ void glds16(const void* g, void* l) {
  __builtin_amdgcn_global_load_lds(
      (const __attribute__((address_space(1))) void*)g,
      (__attribute__((address_space(3))) void*)l, 16, 0, 0);
}

__device__ __forceinline__ void lgkm0() {
  asm volatile("s_waitcnt lgkmcnt(0)" ::: "memory");
}

#define MFMA(a, b, c) __builtin_amdgcn_mfma_f32_16x16x32_bf16((a), (b), (c), 0, 0, 0)

// ---------------- fp32 -> bf16 cast (vector x4) ----------------
__global__ __launch_bounds__(256) void cvt_bf16(const float* __restrict__ src,
                                                u16* __restrict__ dst, int n4) {
  int i = blockIdx.x * 256 + threadIdx.x;
  if (i >= n4) return;
  float4v v = ((const float4v*)src)[i];
  us4 o;
  o[0] = f2bf(v[0]); o[1] = f2bf(v[1]); o[2] = f2bf(v[2]); o[3] = f2bf(v[3]);
  ((us4*)dst)[i] = o;
}

// ---------------- RoPE tables: (L=2048, 32) ----------------
__global__ __launch_bounds__(256) void rope_tables(float* __restrict__ cos_t,
                                                   float* __restrict__ sin_t) {
  int i = blockIdx.x * 256 + threadIdx.x;
  if (i >= 2048 * 32) return;
  int t = i >> 5, fi = i & 31;
  float inv = powf(10000.f, -(float)fi / 32.f);
  float ang = (float)t * inv;
  cos_t[i] = cosf(ang);
  sin_t[i] = sinf(ang);
}

// ---------------- bf16 GEMM, C = A(MxK) * B(NxK)^T, fp32 out ----------------
__global__ __launch_bounds__(256) void gemm_bt(const u16* __restrict__ A,
                                               const u16* __restrict__ B,
                                               float* __restrict__ C,
                                               int M, int N, int K) {
  __shared__ u16 As[128 * 32];
  __shared__ u16 Bs[128 * 32];
  const int tid = threadIdx.x;
  const int w = tid >> 6, l = tid & 63;
  const int wr = w >> 1, wc = w & 1;
  const int lrow = l & 15, lk = (l >> 4) * 8, jr = (l >> 4) * 4;

  f32x4 acc[4][4];
#pragma unroll
  for (int m = 0; m < 4; ++m)
#pragma unroll
    for (int n = 0; n < 4; ++n) acc[m][n] = f32x4{0.f, 0.f, 0.f, 0.f};

  const int st_row = tid >> 2;
  const int st_k = (tid & 3) * 8;
  const u16* a0 = A + (size_t)(blockIdx.x * 128 + st_row) * K + st_k;
  const u16* a1 = a0 + (size_t)64 * K;
  const u16* b0 = B + (size_t)(blockIdx.y * 128 + st_row) * K + st_k;
  const u16* b1 = b0 + (size_t)64 * K;

  u16* Ad0 = &As[w * 512];
  u16* Ad1 = &As[2048 + w * 512];
  u16* Bd0 = &Bs[w * 512];
  u16* Bd1 = &Bs[2048 + w * 512];

  for (int k0 = 0; k0 < K; k0 += 32) {
    glds16(a0, Ad0);
    glds16(a1, Ad1);
    glds16(b0, Bd0);
    glds16(b1, Bd1);
    a0 += 32; a1 += 32; b0 += 32; b1 += 32;
    __syncthreads();
    bf16x8 af[4], bfr[4];
#pragma unroll
    for (int m = 0; m < 4; ++m)
      af[m] = *(const bf16x8*)&As[(wr * 64 + m * 16 + lrow) * 32 + lk];
#pragma unroll
    for (int n = 0; n < 4; ++n)
      bfr[n] = *(const bf16x8*)&Bs[(wc * 64 + n * 16 + lrow) * 32 + lk];
#pragma unroll
    for (int m = 0; m < 4; ++m)
#pragma unroll
      for (int n = 0; n < 4; ++n)
        acc[m][n] = MFMA(af[m], bfr[n], acc[m][n]);
    __syncthreads();
  }

  float* Cp = C + (size_t)(blockIdx.x * 128 + wr * 64) * N + blockIdx.y * 128 + wc * 64;
#pragma unroll
  for (int m = 0; m < 4; ++m)
#pragma unroll
    for (int n = 0; n < 4; ++n)
#pragma unroll
      for (int j = 0; j < 4; ++j)
        Cp[(size_t)(m * 16 + jr + j) * N + n * 16 + lrow] = acc[m][n][j];
}

// ---------------- RoPE apply + layout ----------------
__global__ __launch_bounds__(256) void rope_apply(
    const float* __restrict__ qkv, const float* __restrict__ cos_t,
    const float* __restrict__ sin_t, u16* __restrict__ q_r,
    u16* __restrict__ k_r, u16* __restrict__ v_t) {
  int idx = blockIdx.x * 256 + threadIdx.x;
  if (idx >= 2 * 2048 * 3072) return;
  int c = idx % 3072;
  int bl = idx / 3072;
  int l = bl & 2047, b = bl >> 11;
  float val = qkv[idx];
  if (c < 2048) {              // Q
    int h = c >> 6, d = c & 63;
    float cs = cos_t[l * 32 + (d & 31)];
    float sn = sin_t[l * 32 + (d & 31)];
    float other = qkv[(size_t)bl * 3072 + h * 64 + ((d < 32) ? d + 32 : d - 32)];
    float r = (d < 32) ? (val * cs - other * sn) : (val * cs + other * sn);
    q_r[(((size_t)b * 32 + h) * 2048 + l) * 64 + d] = f2bf(r);
  } else if (c < 2560) {       // K
    int cc = c - 2048, h = cc >> 6, d = cc & 63;
    float cs = cos_t[l * 32 + (d & 31)];
    float sn = sin_t[l * 32 + (d & 31)];
    float other = qkv[(size_t)bl * 3072 + 2048 + h * 64 + ((d < 32) ? d + 32 : d - 32)];
    float r = (d < 32) ? (val * cs - other * sn) : (val * cs + other * sn);
    k_r[(((size_t)b * 8 + h) * 2048 + l) * 64 + d] = f2bf(r);
  } else {                     // V (transposed store)
    int cc = c - 2560, h = cc >> 6, d = cc & 63;
    v_t[(((size_t)b * 8 + h) * 64 + d) * 2048 + l] = f2bf(val);
  }
}

// ---------------- causal GQA flash attention v2 ----------------
// Block: 4 waves = 4 q-heads of one kv-group, 32 q-rows each. KVBLK=64.
// Swapped QK^T (mfma(K,Q)) -> lane-local softmax. XOR-swizzled LDS tiles.
__global__ __launch_bounds__(256) void attn2(const u16* __restrict__ q_r,
                                             const u16* __restrict__ k_r,
                                             const u16* __restrict__ v_t,
                                             u16* __restrict__ attn_o) {
  __shared__ u16 Kl[2][64 * 64];    // [buf][kv][d] swizzled
  __shared__ u16 Vl[2][64 * 64];    // [buf][d][kv] swizzled
  __shared__ u16 Pl[4][32 * 64];    // per-wave [q][kv] swizzled
  __shared__ float Al[4][2][16];    // per-wave alpha/lsum transpose

  const int bid = blockIdx.x;           // 1024 blocks
  const int q0 = (63 - (bid >> 4)) * 32;  // longest blocks first
  const int bk = bid & 15;
  const int b = bk >> 3, kvh = bk & 7;

  const int tid = threadIdx.x;
  const int w = tid >> 6;               // wave = q-head within kv group
  const int l = tid & 63;
  const int h = kvh * 4 + w;
  const int lr = l & 15, lg = l >> 4;

  const u16* Qp = q_r + (((size_t)(b * 32 + h)) * 2048 + q0) * 64;
  const u16* Kp = k_r + ((size_t)(b * 8 + kvh)) * 2048 * 64;
  const u16* Vp = v_t + ((size_t)(b * 8 + kvh)) * 64 * 2048;

  // Q fragments [qhalf][khalf], registers for whole kernel
  bf16x8 qf[2][2];
#pragma unroll
  for (int qh = 0; qh < 2; ++qh)
#pragma unroll
    for (int kh = 0; kh < 2; ++kh)
      qf[qh][kh] = *(const bf16x8*)&Qp[(qh * 16 + lr) * 64 + kh * 32 + lg * 8];

  f32x4 o[2][4];
#pragma unroll
  for (int qh = 0; qh < 2; ++qh)
#pragma unroll
    for (int nf = 0; nf < 4; ++nf) o[qh][nf] = f32x4{0.f, 0.f, 0.f, 0.f};
  float m[2] = {-1e30f, -1e30f}, ls[2] = {0.f, 0.f};

  const int sr = l >> 3;            // staging row-within-8
  const int sc = (l & 7) ^ sr;      // pre-swizzled source chunk (rule 21)
  const int nt = (q0 + 95) >> 6;

  auto stage = [&](int bufi, int t) {
#pragma unroll
    for (int p = 0; p < 2; ++p) {
      const int r = p * 32 + w * 8 + sr;
      glds16(Kp + (size_t)(t * 64 + r) * 64 + sc * 8, &Kl[bufi][(p * 32 + w * 8) * 64]);
      glds16(Vp + (size_t)r * 2048 + t * 64 + sc * 8, &Vl[bufi][(p * 32 + w * 8) * 64]);
    }
  };

  stage(0, 0);
  int buf = 0;
  for (int t = 0; t < nt; ++t) {
    __syncthreads();                       // stage(t) landed; prev buf free
    if (t + 1 < nt) stage(buf ^ 1, t + 1); // overlap loads with compute
    const int kv0 = t * 64;

    // ---- QK^T (swapped: A=K rows, B=Q rows) ----
    f32x4 s[2][4];
#pragma unroll
    for (int qh = 0; qh < 2; ++qh)
#pragma unroll
      for (int kv4 = 0; kv4 < 4; ++kv4) s[qh][kv4] = f32x4{0.f, 0.f, 0.f, 0.f};
    const int swz = (lr & 7) << 4;
#pragma unroll
    for (int kv4 = 0; kv4 < 4; ++kv4) {
      const int kvr = kv4 * 16 + lr;
#pragma unroll
      for (int kh = 0; kh < 2; ++kh) {
        bf16x8 kf = *(const bf16x8*)((const char*)&Kl[buf][kvr * 64] +
                                     ((kh * 64 + lg * 16) ^ swz));
        s[0][kv4] = MFMA(kf, qf[0][kh], s[0][kv4]);
        s[1][kv4] = MFMA(kf, qf[1][kh], s[1][kv4]);
      }
    }

    const bool full = (kv0 + 63 <= q0);    // no masking anywhere in block
    // ---- softmax (lane-local: lane lr owns q-row q0+qh*16+lr) ----
#pragma unroll
    for (int qh = 0; qh < 2; ++qh) {
      const int qrow = q0 + qh * 16 + lr;
      float pm = -1e30f;
#pragma unroll
      for (int kv4 = 0; kv4 < 4; ++kv4)
#pragma unroll
        for (int j = 0; j < 4; ++j) {
          float v = s[qh][kv4][j] * 0.125f;
          if (!full && (kv0 + kv4 * 16 + lg * 4 + j) > qrow) v = -1e30f;
          s[qh][kv4][j] = v;
          pm = fmaxf(pm, v);
        }
      pm = fmaxf(pm, __shfl_xor(pm, 16));
      pm = fmaxf(pm, __shfl_xor(pm, 32));
      if (!__all(pm <= m[qh])) {
        const float mn = fmaxf(m[qh], pm);
        const float al = __expf(m[qh] - mn);
        m[qh] = mn;
        ls[qh] *= al;
        Al[w][qh][lr] = al;                // all lg groups write same value
        lgkm0();
        const f32x4 a4 = *(const f32x4*)&Al[w][qh][lg * 4];
#pragma unroll
        for (int nf = 0; nf < 4; ++nf)
#pragma unroll
          for (int j = 0; j < 4; ++j) o[qh][nf][j] *= a4[j];
      }
      float rs = 0.f;
#pragma unroll
      for (int kv4 = 0; kv4 < 4; ++kv4) {
        us4 pk;
#pragma unroll
        for (int j = 0; j < 4; ++j) {
          const float p = __expf(s[qh][kv4][j] - m[qh]);
          rs += p;
          pk[j] = f2bf(p);
        }
        *(us4*)((char*)&Pl[w][(qh * 16 + lr) * 64] +
                ((kv4 * 32 + lg * 8) ^ swz)) = pk;
      }
      rs += __shfl_xor(rs, 16);
      rs += __shfl_xor(rs, 32);
      ls[qh] += rs;
    }

    // ---- PV: A=P (A-frag from Pl), B=V^T rows from Vl ----
    lgkm0();
#pragma unroll
    for (int k2 = 0; k2 < 2; ++k2) {
      bf16x8 pa[2];
#pragma unroll
      for (int qh = 0; qh < 2; ++qh)
        pa[qh] = *(const bf16x8*)((const char*)&Pl[w][(qh * 16 + lr) * 64] +
                                  ((k2 * 64 + lg * 16) ^ swz));
#pragma unroll
      for (int nf = 0; nf < 4; ++nf) {
        const int d = nf * 16 + lr;
        bf16x8 bv = *(const bf16x8*)((const char*)&Vl[buf][d * 64] +
                                     ((k2 * 64 + lg * 16) ^ swz));
        o[0][nf] = MFMA(pa[0], bv, o[0][nf]);
        o[1][nf] = MFMA(pa[1], bv, o[1][nf]);
      }
    }
    buf ^= 1;
  }

  // ---- epilogue: transpose lsum, divide, store ----
  Al[w][0][lr] = ls[0];
  Al[w][1][lr] = ls[1];
  lgkm0();
  u16* Op = attn_o + (size_t)b * 2048 * 2048 + h * 64;
#pragma unroll
  for (int qh = 0; qh < 2; ++qh) {
    const f32x4 l4 = *(const f32x4*)&Al[w][qh][lg * 4];
#pragma unroll
    for (int j = 0; j < 4; ++j) {
      const float inv = __builtin_amdgcn_rcpf(l4[j]);
      const int row = q0 + qh * 16 + lg * 4 + j;
#pragma unroll
      for (int nf = 0; nf < 4; ++nf)
        Op[(size_t)row * 2048 + nf * 16 + lr] = f2bf(o[qh][nf][j] * inv);
    }
  }
}

// ---------------- launch ----------------
extern "C" void kernel_launch(void* const* d_in, const int* in_sizes, int n_in,
                              void* d_out, int out_size, void* d_ws, size_t ws_size,
                              hipStream_t stream) {
  const float* x = (const float*)d_in[0];
  const float* wq = (const float*)d_in[1];
  const float* wk = (const float*)d_in[2];
  const float* wv = (const float*)d_in[3];
  const float* wo = (const float*)d_in[4];
  float* out = (float*)d_out;

  char* p = (char*)d_ws;
  auto alloc = [&](size_t bytes) {
    char* r = p;
    p += (bytes + 255) & ~(size_t)255;
    return r;
  };
  u16* x_bf   = (u16*)alloc((size_t)8388608 * 2);
  u16* wqkv   = (u16*)alloc((size_t)3072 * 2048 * 2);
  u16* wo_bf  = (u16*)alloc((size_t)2048 * 2048 * 2);
  float* qkv  = (float*)alloc((size_t)4096 * 3072 * 4);
  u16* q_r    = (u16*)alloc((size_t)8388608 * 2);
  u16* k_r    = (u16*)alloc((size_t)2097152 * 2);
  u16* v_t    = (u16*)alloc((size_t)2097152 * 2);
  u16* attn_o = (u16*)alloc((size_t)8388608 * 2);
  float* cos_t = (float*)alloc((size_t)65536 * 4);
  float* sin_t = (float*)alloc((size_t)65536 * 4);

  cvt_bf16<<<8192, 256, 0, stream>>>(x, x_bf, 2097152);
  cvt_bf16<<<4096, 256, 0, stream>>>(wq, wqkv, 1048576);
  cvt_bf16<<<1024, 256, 0, stream>>>(wk, wqkv + (size_t)2048 * 2048, 262144);
  cvt_bf16<<<1024, 256, 0, stream>>>(wv, wqkv + (size_t)2560 * 2048, 262144);
  cvt_bf16<<<4096, 256, 0, stream>>>(wo, wo_bf, 1048576);
  rope_tables<<<256, 256, 0, stream>>>(cos_t, sin_t);

  gemm_bt<<<dim3(32, 24), 256, 0, stream>>>(x_bf, wqkv, qkv, 4096, 3072, 2048);

  rope_apply<<<49152, 256, 0, stream>>>(qkv, cos_t, sin_t, q_r, k_r, v_t);

  attn2<<<1024, 256, 0, stream>>>(q_r, k_r, v_t, attn_o);

  gemm_bt<<<dim3(32, 16), 256, 0, stream>>>(attn_o, wo_bf, out, 4096, 2048, 2048);
}

// Round 3
// 358.718 us; speedup vs baseline: 1.6674x; 1.0391x over previous
//
#include <hip/hip_runtime.h>

using u16 = unsigned short;
typedef __attribute__((ext_vector_type(8))) short bf16x8;
typedef __attribute__((ext_vector_type(4))) float f32x4;
typedef __attribute__((ext_vector_type(4))) float float4v;
typedef __attribute__((ext_vector_type(4))) unsigned short us4;

__device__ __forceinline__ u16 f2bf(float f) {
  union { float f; unsigned u; } v; v.f = f;
  unsigned r = v.u + 0x7fffu + ((v.u >> 16) & 1u);
  return (u16)(r >> 16);
}

__device__ __forceinline__ void glds16(const void* g, void* l) {
  __builtin_amdgcn_global_load_lds(
      (const __attribute__((address_space(1))) void*)g,
      (__attribute__((address_space(3))) void*)l, 16, 0, 0);
}

__device__ __forceinline__ void lgkm0() {
  asm volatile("s_waitcnt lgkmcnt(0)" ::: "memory");
}

#define MFMA(a, b, c) __builtin_amdgcn_mfma_f32_16x16x32_bf16((a), (b), (c), 0, 0, 0)

// scale folded into Q at projection time: 1/sqrt(64) * log2(e)
#define QSCALE 0.1803368801111601f

// ---------------- fp32 -> bf16 cast (vector x4) ----------------
__global__ __launch_bounds__(256) void cvt_bf16(const float* __restrict__ src,
                                                u16* __restrict__ dst, int n4) {
  int i = blockIdx.x * 256 + threadIdx.x;
  if (i >= n4) return;
  float4v v = ((const float4v*)src)[i];
  us4 o;
  o[0] = f2bf(v[0]); o[1] = f2bf(v[1]); o[2] = f2bf(v[2]); o[3] = f2bf(v[3]);
  ((us4*)dst)[i] = o;
}

// ---------------- RoPE cos/sin table: (L=2048, 32) float2 ----------------
__global__ __launch_bounds__(256) void rope_cs(float2* __restrict__ cs) {
  int i = blockIdx.x * 256 + threadIdx.x;
  if (i >= 2048 * 32) return;
  int t = i >> 5, fi = i & 31;
  float inv = powf(10000.f, -(float)fi / 32.f);
  float ang = (float)t * inv;
  cs[i] = make_float2(cosf(ang), sinf(ang));
}

// ---------------- plain bf16 GEMM, C = A(MxK) * B(NxK)^T, fp32 out --------
__global__ __launch_bounds__(256) void gemm_bt(const u16* __restrict__ A,
                                               const u16* __restrict__ B,
                                               float* __restrict__ C,
                                               int M, int N, int K) {
  __shared__ u16 As[128 * 32];
  __shared__ u16 Bs[128 * 32];
  const int tid = threadIdx.x;
  const int w = tid >> 6, l = tid & 63;
  const int wr = w >> 1, wc = w & 1;
  const int lrow = l & 15, lk = (l >> 4) * 8, jr = (l >> 4) * 4;

  f32x4 acc[4][4];
#pragma unroll
  for (int m = 0; m < 4; ++m)
#pragma unroll
    for (int n = 0; n < 4; ++n) acc[m][n] = f32x4{0.f, 0.f, 0.f, 0.f};

  const int st_row = tid >> 2;
  const int st_k = (tid & 3) * 8;
  const u16* a0 = A + (size_t)(blockIdx.x * 128 + st_row) * K + st_k;
  const u16* a1 = a0 + (size_t)64 * K;
  const u16* b0 = B + (size_t)(blockIdx.y * 128 + st_row) * K + st_k;
  const u16* b1 = b0 + (size_t)64 * K;

  u16* Ad0 = &As[w * 512];
  u16* Ad1 = &As[2048 + w * 512];
  u16* Bd0 = &Bs[w * 512];
  u16* Bd1 = &Bs[2048 + w * 512];

  for (int k0 = 0; k0 < K; k0 += 32) {
    glds16(a0, Ad0);
    glds16(a1, Ad1);
    glds16(b0, Bd0);
    glds16(b1, Bd1);
    a0 += 32; a1 += 32; b0 += 32; b1 += 32;
    __syncthreads();
    bf16x8 af[4], bfr[4];
#pragma unroll
    for (int m = 0; m < 4; ++m)
      af[m] = *(const bf16x8*)&As[(wr * 64 + m * 16 + lrow) * 32 + lk];
#pragma unroll
    for (int n = 0; n < 4; ++n)
      bfr[n] = *(const bf16x8*)&Bs[(wc * 64 + n * 16 + lrow) * 32 + lk];
#pragma unroll
    for (int m = 0; m < 4; ++m)
#pragma unroll
      for (int n = 0; n < 4; ++n)
        acc[m][n] = MFMA(af[m], bfr[n], acc[m][n]);
    __syncthreads();
  }

  float* Cp = C + (size_t)(blockIdx.x * 128 + wr * 64) * N + blockIdx.y * 128 + wc * 64;
#pragma unroll
  for (int m = 0; m < 4; ++m)
#pragma unroll
    for (int n = 0; n < 4; ++n)
#pragma unroll
      for (int j = 0; j < 4; ++j)
        Cp[(size_t)(m * 16 + jr + j) * N + n * 16 + lrow] = acc[m][n][j];
}

// ---------------- QKV GEMM with fused RoPE + layout epilogue --------------
// A = x_bf (4096 x 2048), B = wqkv (3072 x 2048)^T.
// by 0..15: Q cols -> rope, *QSCALE, q_r (B,32,L,64)
// by 16..19: K cols -> rope, k_r (B,8,L,64)
// by 20..23: V cols -> v_t (B,8,64,L) transposed
__global__ __launch_bounds__(256) void gemm_qkv(const u16* __restrict__ A,
                                                const u16* __restrict__ B,
                                                const float2* __restrict__ cs,
                                                u16* __restrict__ q_r,
                                                u16* __restrict__ k_r,
                                                u16* __restrict__ v_t) {
  const int K = 2048;
  __shared__ u16 As[128 * 32];
  __shared__ u16 Bs[128 * 32];
  const int tid = threadIdx.x;
  const int w = tid >> 6, l = tid & 63;
  const int wr = w >> 1, wc = w & 1;
  const int lrow = l & 15, lk = (l >> 4) * 8, jr = (l >> 4) * 4;

  f32x4 acc[4][4];
#pragma unroll
  for (int m = 0; m < 4; ++m)
#pragma unroll
    for (int n = 0; n < 4; ++n) acc[m][n] = f32x4{0.f, 0.f, 0.f, 0.f};

  const int st_row = tid >> 2;
  const int st_k = (tid & 3) * 8;
  const u16* a0 = A + (size_t)(blockIdx.x * 128 + st_row) * K + st_k;
  const u16* a1 = a0 + (size_t)64 * K;
  const u16* b0 = B + (size_t)(blockIdx.y * 128 + st_row) * K + st_k;
  const u16* b1 = b0 + (size_t)64 * K;

  u16* Ad0 = &As[w * 512];
  u16* Ad1 = &As[2048 + w * 512];
  u16* Bd0 = &Bs[w * 512];
  u16* Bd1 = &Bs[2048 + w * 512];

  for (int k0 = 0; k0 < K; k0 += 32) {
    glds16(a0, Ad0);
    glds16(a1, Ad1);
    glds16(b0, Bd0);
    glds16(b1, Bd1);
    a0 += 32; a1 += 32; b0 += 32; b1 += 32;
    __syncthreads();
    bf16x8 af[4], bfr[4];
#pragma unroll
    for (int m = 0; m < 4; ++m)
      af[m] = *(const bf16x8*)&As[(wr * 64 + m * 16 + lrow) * 32 + lk];
#pragma unroll
    for (int n = 0; n < 4; ++n)
      bfr[n] = *(const bf16x8*)&Bs[(wc * 64 + n * 16 + lrow) * 32 + lk];
#pragma unroll
    for (int m = 0; m < 4; ++m)
#pragma unroll
      for (int n = 0; n < 4; ++n)
        acc[m][n] = MFMA(af[m], bfr[n], acc[m][n]);
    __syncthreads();
  }

  const int cb = blockIdx.y * 128 + wc * 64;   // wave's global col base (64-blk)
  const int rowbase = blockIdx.x * 128 + wr * 64;

  if (cb < 2560) {
    // ---- Q or K with RoPE ----
    const bool isQ = (cb < 2048);
    const int h = (isQ ? cb : cb - 2048) >> 6;
    u16* dst = isQ ? q_r : k_r;
    const int nh = isQ ? 32 : 8;
#pragma unroll
    for (int m = 0; m < 4; ++m) {
#pragma unroll
      for (int j = 0; j < 4; ++j) {
        const int row = rowbase + m * 16 + jr + j;
        const int b = row >> 11, ll = row & 2047;
        const float2 c0 = cs[ll * 32 + lrow];        // n even (d&31 = lrow)
        const float2 c1 = cs[ll * 32 + 16 + lrow];   // n odd
        u16* op = dst + (((size_t)b * nh + h) * 2048 + ll) * 64;
#pragma unroll
        for (int n = 0; n < 4; ++n) {
          const float val = acc[m][n][j];
          const float oth = acc[m][n ^ 2][j];
          const float cx = (n & 1) ? c1.x : c0.x;
          const float sy = (n & 1) ? c1.y : c0.y;
          float r = (n < 2) ? (val * cx - oth * sy) : (val * cx + oth * sy);
          if (isQ) r *= QSCALE;
          op[n * 16 + lrow] = f2bf(r);
        }
      }
    }
  } else {
    // ---- V: transposed store (B,8,64,L), packed 4 consecutive l ----
    const int h = (cb - 2560) >> 6;
#pragma unroll
    for (int m = 0; m < 4; ++m) {
      const int row0 = rowbase + m * 16 + jr;
      const int b = row0 >> 11, l0 = row0 & 2047;
#pragma unroll
      for (int n = 0; n < 4; ++n) {
        const int d = n * 16 + lrow;
        us4 pk;
#pragma unroll
        for (int j = 0; j < 4; ++j) pk[j] = f2bf(acc[m][n][j]);
        *(us4*)&v_t[(((size_t)b * 8 + h) * 64 + d) * 2048 + l0] = pk;
      }
    }
  }
}

// ---------------- causal GQA flash attention v3 ----------------
// Q pre-scaled by 1/sqrt(d)*log2e at projection -> exp2 domain softmax.
// Exactly one diagonal (masked) tile per block; full tiles skip mask ops.
__global__ __launch_bounds__(256) void attn3(const u16* __restrict__ q_r,
                                             const u16* __restrict__ k_r,
                                             const u16* __restrict__ v_t,
                                             u16* __restrict__ attn_o) {
  __shared__ u16 Kl[2][64 * 64];    // [buf][kv][d] swizzled
  __shared__ u16 Vl[2][64 * 64];    // [buf][d][kv] swizzled
  __shared__ u16 Pl[4][32 * 64];    // per-wave [q][kv] swizzled
  __shared__ float Al[4][2][16];    // per-wave alpha/lsum transpose

  const int bid = blockIdx.x;             // 1024 blocks
  const int q0 = (63 - (bid >> 4)) * 32;  // longest blocks first
  const int bk = bid & 15;
  const int b = bk >> 3, kvh = bk & 7;

  const int tid = threadIdx.x;
  const int w = tid >> 6;                 // wave = q-head within kv group
  const int l = tid & 63;
  const int h = kvh * 4 + w;
  const int lr = l & 15, lg = l >> 4;

  const u16* Qp = q_r + (((size_t)(b * 32 + h)) * 2048 + q0) * 64;
  const u16* Kp = k_r + ((size_t)(b * 8 + kvh)) * 2048 * 64;
  const u16* Vp = v_t + ((size_t)(b * 8 + kvh)) * 64 * 2048;

  bf16x8 qf[2][2];
#pragma unroll
  for (int qh = 0; qh < 2; ++qh)
#pragma unroll
    for (int kh = 0; kh < 2; ++kh)
      qf[qh][kh] = *(const bf16x8*)&Qp[(qh * 16 + lr) * 64 + kh * 32 + lg * 8];

  f32x4 o[2][4];
#pragma unroll
  for (int qh = 0; qh < 2; ++qh)
#pragma unroll
    for (int nf = 0; nf < 4; ++nf) o[qh][nf] = f32x4{0.f, 0.f, 0.f, 0.f};
  float m[2] = {-1e30f, -1e30f}, ls[2] = {0.f, 0.f};

  const int sr = l >> 3;
  const int sc = (l & 7) ^ sr;            // pre-swizzled source chunk
  const int nt = (q0 + 95) >> 6;
  const int nfull = q0 >> 6;              // exactly nt-1

  auto stage = [&](int bufi, int t) {
#pragma unroll
    for (int p = 0; p < 2; ++p) {
      const int r = p * 32 + w * 8 + sr;
      glds16(Kp + (size_t)(t * 64 + r) * 64 + sc * 8, &Kl[bufi][(p * 32 + w * 8) * 64]);
      glds16(Vp + (size_t)r * 2048 + t * 64 + sc * 8, &Vl[bufi][(p * 32 + w * 8) * 64]);
    }
  };

  stage(0, 0);
  int buf = 0;
  for (int t = 0; t < nt; ++t) {
    __syncthreads();
    if (t + 1 < nt) stage(buf ^ 1, t + 1);
    const int kv0 = t * 64;

    // ---- QK^T (swapped: A=K rows, B=Q rows); result in exp2 domain ----
    f32x4 s[2][4];
#pragma unroll
    for (int qh = 0; qh < 2; ++qh)
#pragma unroll
      for (int kv4 = 0; kv4 < 4; ++kv4) s[qh][kv4] = f32x4{0.f, 0.f, 0.f, 0.f};
    const int swz = (lr & 7) << 4;
#pragma unroll
    for (int kv4 = 0; kv4 < 4; ++kv4) {
      const int kvr = kv4 * 16 + lr;
#pragma unroll
      for (int kh = 0; kh < 2; ++kh) {
        bf16x8 kf = *(const bf16x8*)((const char*)&Kl[buf][kvr * 64] +
                                     ((kh * 64 + lg * 16) ^ swz));
        s[0][kv4] = MFMA(kf, qf[0][kh], s[0][kv4]);
        s[1][kv4] = MFMA(kf, qf[1][kh], s[1][kv4]);
      }
    }

    const bool diag = (t >= nfull);       // uniform: one masked tile per block
#pragma unroll
    for (int qh = 0; qh < 2; ++qh) {
      const int qrow = q0 + qh * 16 + lr;
      if (diag) {
#pragma unroll
        for (int kv4 = 0; kv4 < 4; ++kv4)
#pragma unroll
          for (int j = 0; j < 4; ++j)
            if ((kv0 + kv4 * 16 + lg * 4 + j) > qrow) s[qh][kv4][j] = -1e30f;
      }
      float pm = -1e30f;
#pragma unroll
      for (int kv4 = 0; kv4 < 4; ++kv4)
#pragma unroll
        for (int j = 0; j < 4; ++j) pm = fmaxf(pm, s[qh][kv4][j]);
      pm = fmaxf(pm, __shfl_xor(pm, 16));
      pm = fmaxf(pm, __shfl_xor(pm, 32));
      if (!__all(pm <= m[qh])) {
        const float mn = fmaxf(m[qh], pm);
        const float al = exp2f(m[qh] - mn);
        m[qh] = mn;
        ls[qh] *= al;
        Al[w][qh][lr] = al;
        lgkm0();
        const f32x4 a4 = *(const f32x4*)&Al[w][qh][lg * 4];
#pragma unroll
        for (int nf = 0; nf < 4; ++nf)
#pragma unroll
          for (int j = 0; j < 4; ++j) o[qh][nf][j] *= a4[j];
      }
      float rs = 0.f;
#pragma unroll
      for (int kv4 = 0; kv4 < 4; ++kv4) {
        us4 pk;
#pragma unroll
        for (int j = 0; j < 4; ++j) {
          const float p = exp2f(s[qh][kv4][j] - m[qh]);
          rs += p;
          pk[j] = f2bf(p);
        }
        *(us4*)((char*)&Pl[w][(qh * 16 + lr) * 64] +
                ((kv4 * 32 + lg * 8) ^ swz)) = pk;
      }
      rs += __shfl_xor(rs, 16);
      rs += __shfl_xor(rs, 32);
      ls[qh] += rs;
    }

    // ---- PV: A=P, B=V^T rows ----
    lgkm0();
#pragma unroll
    for (int k2 = 0; k2 < 2; ++k2) {
      bf16x8 pa[2];
#pragma unroll
      for (int qh = 0; qh < 2; ++qh)
        pa[qh] = *(const bf16x8*)((const char*)&Pl[w][(qh * 16 + lr) * 64] +
                                  ((k2 * 64 + lg * 16) ^ swz));
#pragma unroll
      for (int nf = 0; nf < 4; ++nf) {
        const int d = nf * 16 + lr;
        bf16x8 bv = *(const bf16x8*)((const char*)&Vl[buf][d * 64] +
                                     ((k2 * 64 + lg * 16) ^ swz));
        o[0][nf] = MFMA(pa[0], bv, o[0][nf]);
        o[1][nf] = MFMA(pa[1], bv, o[1][nf]);
      }
    }
    buf ^= 1;
  }

  // ---- epilogue ----
  Al[w][0][lr] = ls[0];
  Al[w][1][lr] = ls[1];
  lgkm0();
  u16* Op = attn_o + (size_t)b * 2048 * 2048 + h * 64;
#pragma unroll
  for (int qh = 0; qh < 2; ++qh) {
    const f32x4 l4 = *(const f32x4*)&Al[w][qh][lg * 4];
#pragma unroll
    for (int j = 0; j < 4; ++j) {
      const float inv = __builtin_amdgcn_rcpf(l4[j]);
      const int row = q0 + qh * 16 + lg * 4 + j;
#pragma unroll
      for (int nf = 0; nf < 4; ++nf)
        Op[(size_t)row * 2048 + nf * 16 + lr] = f2bf(o[qh][nf][j] * inv);
    }
  }
}

// ---------------- launch ----------------
extern "C" void kernel_launch(void* const* d_in, const int* in_sizes, int n_in,
                              void* d_out, int out_size, void* d_ws, size_t ws_size,
                              hipStream_t stream) {
  const float* x = (const float*)d_in[0];
  const float* wq = (const float*)d_in[1];
  const float* wk = (const float*)d_in[2];
  const float* wv = (const float*)d_in[3];
  const float* wo = (const float*)d_in[4];
  float* out = (float*)d_out;

  char* p = (char*)d_ws;
  auto alloc = [&](size_t bytes) {
    char* r = p;
    p += (bytes + 255) & ~(size_t)255;
    return r;
  };
  u16* x_bf    = (u16*)alloc((size_t)8388608 * 2);
  u16* wqkv    = (u16*)alloc((size_t)3072 * 2048 * 2);
  u16* wo_bf   = (u16*)alloc((size_t)2048 * 2048 * 2);
  u16* q_r     = (u16*)alloc((size_t)8388608 * 2);
  u16* k_r     = (u16*)alloc((size_t)2097152 * 2);
  u16* v_t     = (u16*)alloc((size_t)2097152 * 2);
  u16* attn_o  = (u16*)alloc((size_t)8388608 * 2);
  float2* cs   = (float2*)alloc((size_t)65536 * 8);

  cvt_bf16<<<8192, 256, 0, stream>>>(x, x_bf, 2097152);
  cvt_bf16<<<4096, 256, 0, stream>>>(wq, wqkv, 1048576);
  cvt_bf16<<<1024, 256, 0, stream>>>(wk, wqkv + (size_t)2048 * 2048, 262144);
  cvt_bf16<<<1024, 256, 0, stream>>>(wv, wqkv + (size_t)2560 * 2048, 262144);
  cvt_bf16<<<4096, 256, 0, stream>>>(wo, wo_bf, 1048576);
  rope_cs<<<256, 256, 0, stream>>>(cs);

  // QKV projection with fused RoPE/layout: (4096x2048) x (3072x2048)^T
  gemm_qkv<<<dim3(32, 24), 256, 0, stream>>>(x_bf, wqkv, cs, q_r, k_r, v_t);

  attn3<<<1024, 256, 0, stream>>>(q_r, k_r, v_t, attn_o);

  // output projection: (4096x2048) x (2048x2048)^T -> (4096x2048)
  gemm_bt<<<dim3(32, 16), 256, 0, stream>>>(attn_o, wo_bf, out, 4096, 2048, 2048);
}

// Round 4
// 330.655 us; speedup vs baseline: 1.8089x; 1.0849x over previous
//
#include <hip/hip_runtime.h>

using u16 = unsigned short;
using u32 = unsigned int;
typedef __attribute__((ext_vector_type(8))) short bf16x8;
typedef __attribute__((ext_vector_type(4))) float f32x4;
typedef __attribute__((ext_vector_type(4))) float float4v;
typedef __attribute__((ext_vector_type(4))) unsigned short us4;
typedef __attribute__((ext_vector_type(2))) unsigned int u32x2;

__device__ __forceinline__ u16 f2bf(float f) {
  union { float f; unsigned u; } v; v.f = f;
  unsigned r = v.u + 0x7fffu + ((v.u >> 16) & 1u);
  return (u16)(r >> 16);
}

__device__ __forceinline__ u32 cvtpk(float a, float b) {
  u32 r;
  asm("v_cvt_pk_bf16_f32 %0, %1, %2" : "=v"(r) : "v"(a), "v"(b));
  return r;
}

__device__ __forceinline__ void glds16(const void* g, void* l) {
  __builtin_amdgcn_global_load_lds(
      (const __attribute__((address_space(1))) void*)g,
      (__attribute__((address_space(3))) void*)l, 16, 0, 0);
}

__device__ __forceinline__ void lgkm0() {
  asm volatile("s_waitcnt lgkmcnt(0)" ::: "memory");
}

#define MFMA(a, b, c) __builtin_amdgcn_mfma_f32_16x16x32_bf16((a), (b), (c), 0, 0, 0)

// scale folded into Q at projection time: 1/sqrt(64) * log2(e)
#define QSCALE 0.1803368801111601f

// ---------------- fused fp32 -> bf16 cast for all 5 inputs ----------------
// f4-unit ranges: x[0,2097152) wq[..+1048576) wk[..+262144) wv[..+262144) wo[..+1048576)
__global__ __launch_bounds__(256) void cvt_all(
    const float* __restrict__ x, const float* __restrict__ wq,
    const float* __restrict__ wk, const float* __restrict__ wv,
    const float* __restrict__ wo, u16* __restrict__ x_bf,
    u16* __restrict__ wqkv, u16* __restrict__ wo_bf) {
  int i = blockIdx.x * 256 + threadIdx.x;   // 4718592 total
  const float4v* src;
  us4* dst;
  if (i < 2097152) {
    src = (const float4v*)x + i; dst = (us4*)x_bf + i;
  } else if (i < 3145728) {
    int j = i - 2097152; src = (const float4v*)wq + j; dst = (us4*)wqkv + j;
  } else if (i < 3407872) {
    int j = i - 3145728; src = (const float4v*)wk + j; dst = (us4*)wqkv + 1048576 + j;
  } else if (i < 3670016) {
    int j = i - 3407872; src = (const float4v*)wv + j; dst = (us4*)wqkv + 1310720 + j;
  } else {
    int j = i - 3670016; src = (const float4v*)wo + j; dst = (us4*)wo_bf + j;
  }
  float4v v = *src;
  us4 o;
  o[0] = f2bf(v[0]); o[1] = f2bf(v[1]); o[2] = f2bf(v[2]); o[3] = f2bf(v[3]);
  *dst = o;
}

// ---------------- RoPE cos/sin table: (L=2048, 32) float2 ----------------
__global__ __launch_bounds__(256) void rope_cs(float2* __restrict__ cs) {
  int i = blockIdx.x * 256 + threadIdx.x;
  if (i >= 2048 * 32) return;
  int t = i >> 5, fi = i & 31;
  float inv = powf(10000.f, -(float)fi / 32.f);
  float ang = (float)t * inv;
  cs[i] = make_float2(cosf(ang), sinf(ang));
}

// ---------------- plain bf16 GEMM, C = A(MxK) * B(NxK)^T, fp32 out --------
// 1D grid, XCD-chunked bijective swizzle (nwg % 8 == 0)
__global__ __launch_bounds__(256) void gemm_bt(const u16* __restrict__ A,
                                               const u16* __restrict__ B,
                                               float* __restrict__ C,
                                               int M, int N, int K) {
  __shared__ u16 As[128 * 32];
  __shared__ u16 Bs[128 * 32];
  const int nwg = gridDim.x;
  const int cpx = nwg >> 3;
  const int flat = blockIdx.x;
  const int swb = (flat & 7) * cpx + (flat >> 3);
  const int MT = M >> 7;
  const int bx = swb % MT, by = swb / MT;

  const int tid = threadIdx.x;
  const int w = tid >> 6, l = tid & 63;
  const int wr = w >> 1, wc = w & 1;
  const int lrow = l & 15, lk = (l >> 4) * 8, jr = (l >> 4) * 4;

  f32x4 acc[4][4];
#pragma unroll
  for (int m = 0; m < 4; ++m)
#pragma unroll
    for (int n = 0; n < 4; ++n) acc[m][n] = f32x4{0.f, 0.f, 0.f, 0.f};

  const int st_row = tid >> 2;
  const int st_k = (tid & 3) * 8;
  const u16* a0 = A + (size_t)(bx * 128 + st_row) * K + st_k;
  const u16* a1 = a0 + (size_t)64 * K;
  const u16* b0 = B + (size_t)(by * 128 + st_row) * K + st_k;
  const u16* b1 = b0 + (size_t)64 * K;

  u16* Ad0 = &As[w * 512];
  u16* Ad1 = &As[2048 + w * 512];
  u16* Bd0 = &Bs[w * 512];
  u16* Bd1 = &Bs[2048 + w * 512];

  for (int k0 = 0; k0 < K; k0 += 32) {
    glds16(a0, Ad0);
    glds16(a1, Ad1);
    glds16(b0, Bd0);
    glds16(b1, Bd1);
    a0 += 32; a1 += 32; b0 += 32; b1 += 32;
    __syncthreads();
    bf16x8 af[4], bfr[4];
#pragma unroll
    for (int m = 0; m < 4; ++m)
      af[m] = *(const bf16x8*)&As[(wr * 64 + m * 16 + lrow) * 32 + lk];
#pragma unroll
    for (int n = 0; n < 4; ++n)
      bfr[n] = *(const bf16x8*)&Bs[(wc * 64 + n * 16 + lrow) * 32 + lk];
#pragma unroll
    for (int m = 0; m < 4; ++m)
#pragma unroll
      for (int n = 0; n < 4; ++n)
        acc[m][n] = MFMA(af[m], bfr[n], acc[m][n]);
    __syncthreads();
  }

  float* Cp = C + (size_t)(bx * 128 + wr * 64) * N + by * 128 + wc * 64;
#pragma unroll
  for (int m = 0; m < 4; ++m)
#pragma unroll
    for (int n = 0; n < 4; ++n)
#pragma unroll
      for (int j = 0; j < 4; ++j)
        Cp[(size_t)(m * 16 + jr + j) * N + n * 16 + lrow] = acc[m][n][j];
}

// ---------------- QKV GEMM with fused RoPE + layout epilogue --------------
__global__ __launch_bounds__(256) void gemm_qkv(const u16* __restrict__ A,
                                                const u16* __restrict__ B,
                                                const float2* __restrict__ cs,
                                                u16* __restrict__ q_r,
                                                u16* __restrict__ k_r,
                                                u16* __restrict__ v_t) {
  const int K = 2048;
  __shared__ u16 As[128 * 32];
  __shared__ u16 Bs[128 * 32];
  const int nwg = gridDim.x;          // 768
  const int cpx = nwg >> 3;
  const int flat = blockIdx.x;
  const int swb = (flat & 7) * cpx + (flat >> 3);
  const int bx = swb & 31, by = swb >> 5;

  const int tid = threadIdx.x;
  const int w = tid >> 6, l = tid & 63;
  const int wr = w >> 1, wc = w & 1;
  const int lrow = l & 15, lk = (l >> 4) * 8, jr = (l >> 4) * 4;

  f32x4 acc[4][4];
#pragma unroll
  for (int m = 0; m < 4; ++m)
#pragma unroll
    for (int n = 0; n < 4; ++n) acc[m][n] = f32x4{0.f, 0.f, 0.f, 0.f};

  const int st_row = tid >> 2;
  const int st_k = (tid & 3) * 8;
  const u16* a0 = A + (size_t)(bx * 128 + st_row) * K + st_k;
  const u16* a1 = a0 + (size_t)64 * K;
  const u16* b0 = B + (size_t)(by * 128 + st_row) * K + st_k;
  const u16* b1 = b0 + (size_t)64 * K;

  u16* Ad0 = &As[w * 512];
  u16* Ad1 = &As[2048 + w * 512];
  u16* Bd0 = &Bs[w * 512];
  u16* Bd1 = &Bs[2048 + w * 512];

  for (int k0 = 0; k0 < K; k0 += 32) {
    glds16(a0, Ad0);
    glds16(a1, Ad1);
    glds16(b0, Bd0);
    glds16(b1, Bd1);
    a0 += 32; a1 += 32; b0 += 32; b1 += 32;
    __syncthreads();
    bf16x8 af[4], bfr[4];
#pragma unroll
    for (int m = 0; m < 4; ++m)
      af[m] = *(const bf16x8*)&As[(wr * 64 + m * 16 + lrow) * 32 + lk];
#pragma unroll
    for (int n = 0; n < 4; ++n)
      bfr[n] = *(const bf16x8*)&Bs[(wc * 64 + n * 16 + lrow) * 32 + lk];
#pragma unroll
    for (int m = 0; m < 4; ++m)
#pragma unroll
      for (int n = 0; n < 4; ++n)
        acc[m][n] = MFMA(af[m], bfr[n], acc[m][n]);
    __syncthreads();
  }

  const int cb = by * 128 + wc * 64;
  const int rowbase = bx * 128 + wr * 64;

  if (cb < 2560) {
    const bool isQ = (cb < 2048);
    const int h = (isQ ? cb : cb - 2048) >> 6;
    u16* dst = isQ ? q_r : k_r;
    const int nh = isQ ? 32 : 8;
#pragma unroll
    for (int m = 0; m < 4; ++m) {
#pragma unroll
      for (int j = 0; j < 4; ++j) {
        const int row = rowbase + m * 16 + jr + j;
        const int b = row >> 11, ll = row & 2047;
        const float2 c0 = cs[ll * 32 + lrow];
        const float2 c1 = cs[ll * 32 + 16 + lrow];
        u16* op = dst + (((size_t)b * nh + h) * 2048 + ll) * 64;
#pragma unroll
        for (int n = 0; n < 4; ++n) {
          const float val = acc[m][n][j];
          const float oth = acc[m][n ^ 2][j];
          const float cx = (n & 1) ? c1.x : c0.x;
          const float sy = (n & 1) ? c1.y : c0.y;
          float r = (n < 2) ? (val * cx - oth * sy) : (val * cx + oth * sy);
          if (isQ) r *= QSCALE;
          op[n * 16 + lrow] = f2bf(r);
        }
      }
    }
  } else {
    const int h = (cb - 2560) >> 6;
#pragma unroll
    for (int m = 0; m < 4; ++m) {
      const int row0 = rowbase + m * 16 + jr;
      const int b = row0 >> 11, l0 = row0 & 2047;
#pragma unroll
      for (int n = 0; n < 4; ++n) {
        const int d = n * 16 + lrow;
        us4 pk;
#pragma unroll
        for (int j = 0; j < 4; ++j) pk[j] = f2bf(acc[m][n][j]);
        *(us4*)&v_t[(((size_t)b * 8 + h) * 64 + d) * 2048 + l0] = pk;
      }
    }
  }
}

// ---------------- causal GQA flash attention v4 ----------------
// Fixed-base softmax: p = exp2(s) raw (exact after normalization; s bounded).
// No max tracking / rescale. lsum computed by MFMA with a ones B-fragment,
// landing directly in the o[] D-layout (no LDS transpose anywhere).
__global__ __launch_bounds__(256) void attn4(const u16* __restrict__ q_r,
                                             const u16* __restrict__ k_r,
                                             const u16* __restrict__ v_t,
                                             u16* __restrict__ attn_o) {
  __shared__ u16 Kl[2][64 * 64];    // [buf][kv][d] swizzled
  __shared__ u16 Vl[2][64 * 64];    // [buf][d][kv] swizzled
  __shared__ u16 Pl[4][32 * 64];    // per-wave [q][kv] swizzled

  const int bid = blockIdx.x;             // 1024 blocks
  const int q0 = (63 - (bid >> 4)) * 32;  // longest blocks first
  const int bk = bid & 15;
  const int b = bk >> 3, kvh = bk & 7;

  const int tid = threadIdx.x;
  const int w = tid >> 6;                 // wave = q-head within kv group
  const int l = tid & 63;
  const int h = kvh * 4 + w;
  const int lr = l & 15, lg = l >> 4;

  const u16* Qp = q_r + (((size_t)(b * 32 + h)) * 2048 + q0) * 64;
  const u16* Kp = k_r + ((size_t)(b * 8 + kvh)) * 2048 * 64;
  const u16* Vp = v_t + ((size_t)(b * 8 + kvh)) * 64 * 2048;

  bf16x8 qf[2][2];
#pragma unroll
  for (int qh = 0; qh < 2; ++qh)
#pragma unroll
    for (int kh = 0; kh < 2; ++kh)
      qf[qh][kh] = *(const bf16x8*)&Qp[(qh * 16 + lr) * 64 + kh * 32 + lg * 8];

  bf16x8 ones;
#pragma unroll
  for (int i = 0; i < 8; ++i) ones[i] = (short)0x3F80;   // bf16 1.0

  f32x4 o[2][4];
#pragma unroll
  for (int qh = 0; qh < 2; ++qh)
#pragma unroll
    for (int nf = 0; nf < 4; ++nf) o[qh][nf] = f32x4{0.f, 0.f, 0.f, 0.f};
  f32x4 lsv[2] = {f32x4{0.f, 0.f, 0.f, 0.f}, f32x4{0.f, 0.f, 0.f, 0.f}};

  const int sr = l >> 3;
  const int sc = (l & 7) ^ sr;            // pre-swizzled source chunk
  const int nt = (q0 + 95) >> 6;
  const int nfull = q0 >> 6;

  auto stage = [&](int bufi, int t) {
#pragma unroll
    for (int p = 0; p < 2; ++p) {
      const int r = p * 32 + w * 8 + sr;
      glds16(Kp + (size_t)(t * 64 + r) * 64 + sc * 8, &Kl[bufi][(p * 32 + w * 8) * 64]);
      glds16(Vp + (size_t)r * 2048 + t * 64 + sc * 8, &Vl[bufi][(p * 32 + w * 8) * 64]);
    }
  };

  stage(0, 0);
  int buf = 0;
  for (int t = 0; t < nt; ++t) {
    __syncthreads();
    if (t + 1 < nt) stage(buf ^ 1, t + 1);
    const int kv0 = t * 64;

    // ---- QK^T (swapped: A=K rows, B=Q rows); exp2-domain scores ----
    f32x4 s[2][4];
#pragma unroll
    for (int qh = 0; qh < 2; ++qh)
#pragma unroll
      for (int kv4 = 0; kv4 < 4; ++kv4) s[qh][kv4] = f32x4{0.f, 0.f, 0.f, 0.f};
    const int swz = (lr & 7) << 4;
#pragma unroll
    for (int kv4 = 0; kv4 < 4; ++kv4) {
      const int kvr = kv4 * 16 + lr;
#pragma unroll
      for (int kh = 0; kh < 2; ++kh) {
        bf16x8 kf = *(const bf16x8*)((const char*)&Kl[buf][kvr * 64] +
                                     ((kh * 64 + lg * 16) ^ swz));
        s[0][kv4] = MFMA(kf, qf[0][kh], s[0][kv4]);
        s[1][kv4] = MFMA(kf, qf[1][kh], s[1][kv4]);
      }
    }

    const bool diag = (t >= nfull);       // one masked tile per block
#pragma unroll
    for (int qh = 0; qh < 2; ++qh) {
      const int qrow = q0 + qh * 16 + lr;
      if (diag) {
#pragma unroll
        for (int kv4 = 0; kv4 < 4; ++kv4)
#pragma unroll
          for (int j = 0; j < 4; ++j)
            if ((kv0 + kv4 * 16 + lg * 4 + j) > qrow) s[qh][kv4][j] = -1e30f;
      }
#pragma unroll
      for (int kv4 = 0; kv4 < 4; ++kv4) {
        u32x2 pk;
        pk[0] = cvtpk(exp2f(s[qh][kv4][0]), exp2f(s[qh][kv4][1]));
        pk[1] = cvtpk(exp2f(s[qh][kv4][2]), exp2f(s[qh][kv4][3]));
        *(u32x2*)((char*)&Pl[w][(qh * 16 + lr) * 64] +
                  ((kv4 * 32 + lg * 8) ^ swz)) = pk;
      }
    }

    // ---- PV: A=P, B=V^T rows; lsum via ones-fragment MFMA ----
    lgkm0();
#pragma unroll
    for (int k2 = 0; k2 < 2; ++k2) {
      bf16x8 pa[2];
#pragma unroll
      for (int qh = 0; qh < 2; ++qh)
        pa[qh] = *(const bf16x8*)((const char*)&Pl[w][(qh * 16 + lr) * 64] +
                                  ((k2 * 64 + lg * 16) ^ swz));
      lsv[0] = MFMA(pa[0], ones, lsv[0]);
      lsv[1] = MFMA(pa[1], ones, lsv[1]);
#pragma unroll
      for (int nf = 0; nf < 4; ++nf) {
        const int d = nf * 16 + lr;
        bf16x8 bv = *(const bf16x8*)((const char*)&Vl[buf][d * 64] +
                                     ((k2 * 64 + lg * 16) ^ swz));
        o[0][nf] = MFMA(pa[0], bv, o[0][nf]);
        o[1][nf] = MFMA(pa[1], bv, o[1][nf]);
      }
    }
    buf ^= 1;
  }

  // ---- epilogue: lsv already in o[] layout; divide & store ----
  u16* Op = attn_o + (size_t)b * 2048 * 2048 + h * 64;
#pragma unroll
  for (int qh = 0; qh < 2; ++qh) {
#pragma unroll
    for (int j = 0; j < 4; ++j) {
      const float inv = __builtin_amdgcn_rcpf(lsv[qh][j]);
      const int row = q0 + qh * 16 + lg * 4 + j;
#pragma unroll
      for (int nf = 0; nf < 4; ++nf)
        Op[(size_t)row * 2048 + nf * 16 + lr] = f2bf(o[qh][nf][j] * inv);
    }
  }
}

// ---------------- launch ----------------
extern "C" void kernel_launch(void* const* d_in, const int* in_sizes, int n_in,
                              void* d_out, int out_size, void* d_ws, size_t ws_size,
                              hipStream_t stream) {
  const float* x = (const float*)d_in[0];
  const float* wq = (const float*)d_in[1];
  const float* wk = (const float*)d_in[2];
  const float* wv = (const float*)d_in[3];
  const float* wo = (const float*)d_in[4];
  float* out = (float*)d_out;

  char* p = (char*)d_ws;
  auto alloc = [&](size_t bytes) {
    char* r = p;
    p += (bytes + 255) & ~(size_t)255;
    return r;
  };
  u16* x_bf    = (u16*)alloc((size_t)8388608 * 2);
  u16* wqkv    = (u16*)alloc((size_t)3072 * 2048 * 2);
  u16* wo_bf   = (u16*)alloc((size_t)2048 * 2048 * 2);
  u16* q_r     = (u16*)alloc((size_t)8388608 * 2);
  u16* k_r     = (u16*)alloc((size_t)2097152 * 2);
  u16* v_t     = (u16*)alloc((size_t)2097152 * 2);
  u16* attn_o  = (u16*)alloc((size_t)8388608 * 2);
  float2* cs   = (float2*)alloc((size_t)65536 * 8);

  cvt_all<<<18432, 256, 0, stream>>>(x, wq, wk, wv, wo, x_bf, wqkv, wo_bf);
  rope_cs<<<256, 256, 0, stream>>>(cs);

  // QKV projection with fused RoPE/layout: (4096x2048) x (3072x2048)^T
  gemm_qkv<<<768, 256, 0, stream>>>(x_bf, wqkv, cs, q_r, k_r, v_t);

  attn4<<<1024, 256, 0, stream>>>(q_r, k_r, v_t, attn_o);

  // output projection: (4096x2048) x (2048x2048)^T -> (4096x2048)
  gemm_bt<<<512, 256, 0, stream>>>(attn_o, wo_bf, out, 4096, 2048, 2048);
}